// Round 16
// baseline (110.702 us; speedup 1.0000x reference)
//
#include <hip/hip_runtime.h>
#include <hip/hip_fp16.h>
#include <math.h>

// sigAct: u0 = sigmoid(-(lam_b*conv(1-2x))/eps); 5 damped updates.
// conv = separable 17-tap Gaussian (sigma=2); folding: conv(1-2u) = 1-2*blur(u)
// with 0.5-padding (== SAME zero-pad of 1-2u).
// Round-16 = round-14 with FULL-WAVE geometry: TR=16, TC=128 -> h-blur has
// exactly 256 units (16 pair-rows x 16 col-groups), all 4 waves busy, no
// divergent guard (r14: 192/256 threads, 1 wave idle). v-blur indexing
// identical to r14 (verified), constants 64->128, 24->16. sP = 8 KB.
// r15's prefetch/stash additions measured neutral -> reverted (lean r14 epi).
// Lessons: VALU-inst-count is the ONLY lever that moved (r12 -14, r14 -2);
// occupancy (r11), latency packages (r15), fusion (r10), coop (r6) all dead.

#define TR   16
#define TC   128
#define RAD  8
#define HW   512
#define NIMG 24
#define NPIX ((size_t)HW * HW * NIMG)

typedef _Float16 h2 __attribute__((ext_vector_type(2)));
typedef unsigned int uint;

// 1D normalized Gaussian, sigma=2, 17 taps: exp(-(k-8)^2/8) / 5.0131684
#define G0  6.6916e-05f
#define G1  4.3635e-04f
#define G2  2.2159612e-03f
#define G3  8.7643070e-03f
#define G4  2.6995958e-02f
#define G5  6.4759932e-02f
#define G6  1.2098751e-01f
#define G7  1.7603572e-01f
#define G8  1.9947466e-01f

// sigmoid(-z) = 1/(1+exp(z)); inf->0, -inf->1.
__device__ __forceinline__ float inv1pexp(float z) {
    return __builtin_amdgcn_rcpf(1.0f + __expf(z));
}

__device__ __forceinline__ float fdot2f(uint a, h2 b, float c) {
#if __has_builtin(__builtin_amdgcn_fdot2)
    return __builtin_amdgcn_fdot2(__builtin_bit_cast(h2, a), b, c, false);
#else
    h2 av = __builtin_bit_cast(h2, a);
    return (float)av.x * (float)b.x + (float)av.y * (float)b.y + c;
#endif
}
__device__ __forceinline__ float lo16f(uint v) {
    return __half2float(__ushort_as_half((unsigned short)(v & 0xffffu)));
}
__device__ __forceinline__ float hi16f(uint v) {
    return __half2float(__ushort_as_half((unsigned short)(v >> 16)));
}
__device__ __forceinline__ h2 gpair(int i) {
    // (G[2i], G[2i+1]) fp16, compile-time folded (i = 0..7, taps 0..15)
    const float G[16] = { G0,G1,G2,G3,G4,G5,G6,G7,G8,G7,G6,G5,G4,G3,G2,G1 };
    h2 r; r.x = (_Float16)G[2*i]; r.y = (_Float16)G[2*i+1]; return r;
}
__device__ __forceinline__ uint packh2(float lo, float hi) {
    return __builtin_bit_cast(uint, __floats2half2_rn(lo, hi));
}

// 17-tap dot over a 24-half window (12 even-pairs wv + 11 odd-pairs wo):
// outputs at window offsets 2jp (even) and 2jp+1 (odd).
__device__ __forceinline__ void dot17(const uint* wv, const uint* wo,
                                      int jp, float& aE, float& aO) {
    float a0 = 0.f, a1 = 0.f;
#pragma unroll
    for (int i = 0; i < 8; ++i) {
        h2 g = gpair(i);
        a0 = fdot2f(wv[jp + i], g, a0);
        a1 = fdot2f(wo[jp + i], g, a1);
    }
    aE = fmaf(G0, lo16f(wv[jp + 8]), a0);
    aO = fmaf(G0, hi16f(wv[jp + 8]), a1);
}

template<int MODE> // 0=INIT 1=MID 2=FINAL
__global__ __launch_bounds__(256, 6) void sig_step(
    const float* __restrict__ xg, const float* __restrict__ cgl,
    const __half* __restrict__ uin, __half2* __restrict__ xl,
    void* __restrict__ uout)
{
    __shared__ uint sP[16 * 128];   // row-paired h-blur output, 8 KB

    const int t    = threadIdx.x;
    const int img  = blockIdx.z;
    const int row0 = blockIdx.y * TR;
    const int col0 = blockIdx.x * TC;
    const size_t ibase = (size_t)img * HW * HW;

    // ===== h-blur: 256 units = (pair-row rp in [0,16), col-group ci in [0,16)) ====
    {
        const int rp  = t >> 4;               // 0..15
        const int ci  = t & 15;               // 0..15
        const int gc0 = col0 + ci * 8 - RAD;  // window cols [gc0, gc0+24), mult 8
        float aE[2][4], aO[2][4];
#pragma unroll
        for (int rr = 0; rr < 2; ++rr) {
            const int gr = row0 + 2 * rp + rr - RAD;  // halo row 2rp+rr in [0,32)
            uint wv[12];
#pragma unroll
            for (int i = 0; i < 12; ++i) wv[i] = 0x38003800u;  // (0.5,0.5) pad
            if (gr >= 0 && gr < HW) {
                if constexpr (MODE == 0) {
                    const float* xb = xg + ibase + (size_t)gr * HW;
#pragma unroll
                    for (int k = 0; k < 6; ++k) {
                        int s = gc0 + 4 * k;
                        if (s >= 0 && s < HW) {
                            float4 v = *reinterpret_cast<const float4*>(&xb[s]);
                            wv[2*k]   = packh2(v.x, v.y);
                            wv[2*k+1] = packh2(v.z, v.w);
                        }
                    }
                } else {
                    const __half* ub = uin + ibase + (size_t)gr * HW;
#pragma unroll
                    for (int k = 0; k < 3; ++k) {
                        int s = gc0 + 8 * k;
                        if (s >= 0 && s < HW) {
                            uint4 v = *reinterpret_cast<const uint4*>(&ub[s]);
                            wv[4*k+0] = v.x; wv[4*k+1] = v.y;
                            wv[4*k+2] = v.z; wv[4*k+3] = v.w;
                        }
                    }
                }
            }
            uint wo[11];
#pragma unroll
            for (int i = 0; i < 11; ++i)
                wo[i] = __builtin_amdgcn_alignbit(wv[i + 1], wv[i], 16);
#pragma unroll
            for (int jp = 0; jp < 4; ++jp)
                dot17(wv, wo, jp, aE[rr][jp], aO[rr][jp]);
        }
        // pack row-pairs: sP[rp][8ci+j] = (row 2rp, row 2rp+1)
        uint4* orow = reinterpret_cast<uint4*>(&sP[rp * 128 + ci * 8]);
        orow[0] = make_uint4(packh2(aE[0][0], aE[1][0]), packh2(aO[0][0], aO[1][0]),
                             packh2(aE[0][1], aE[1][1]), packh2(aO[0][1], aO[1][1]));
        orow[1] = make_uint4(packh2(aE[0][2], aE[1][2]), packh2(aO[0][2], aO[1][2]),
                             packh2(aE[0][3], aE[1][3]), packh2(aO[0][3], aO[1][3]));
    }
    __syncthreads();

    // ===== v-blur via dot2 (1 col x 8 rows/thread) + pointwise epilogue =====
    const int cc = t & 127;
    const int rg = t >> 7;                 // 2 row groups x 8 rows
    const size_t pbase = ibase + (size_t)(row0 + rg * 8) * HW + (col0 + cc);

    uint p[12];                            // pairs rg*4 .. rg*4+11, column cc
#pragma unroll
    for (int j = 0; j < 12; ++j)
        p[j] = sP[(rg * 4 + j) * 128 + cc];
    uint po[11];
#pragma unroll
    for (int j = 0; j < 11; ++j)
        po[j] = __builtin_amdgcn_alignbit(p[j + 1], p[j], 16);

#pragma unroll
    for (int jp = 0; jp < 4; ++jp) {
        float vE, vO;
        dot17(p, po, jp, vE, vO);
#pragma unroll
        for (int h = 0; h < 2; ++h) {
            int m = 2 * jp + h;
            float v = h ? vO : vE;
            float f = 1.f - 2.f * v;       // == conv(1-2u), SAME zero-pad

            size_t gidx = pbase + (size_t)m * HW;
            if constexpr (MODE == 0) {
                float xv  = xg[gidx];
                float lam = 100.f * inv1pexp(-10.f * cgl[gidx]); // 100*sig(10c)
                xl[gidx] = __floats2half2_rn(xv, lam);
                ((__half*)uout)[gidx] = __float2half(inv1pexp(lam * f * 0.1f));
            } else {
                float2 pr = __half22float2(xl[gidx]);            // (x, lam)
                float uprev = __half2float(uin[gidx]);           // L1/L2-hot
                float tt = (uprev - pr.x) * 10.f + pr.y * f;     // (u-x)/tau+lam*v
                float uu = inv1pexp(tt * 0.1f);                  // sigmoid(-tt/eps)
                float res = 0.5f * (uprev + uu);                 // alpha = 0.5
                if constexpr (MODE == 2) ((float*)uout)[gidx] = res;
                else                     ((__half*)uout)[gidx] = __float2half(res);
            }
        }
    }
}

extern "C" void kernel_launch(void* const* d_in, const int* in_sizes, int n_in,
                              void* d_out, int out_size, void* d_ws, size_t ws_size,
                              hipStream_t stream) {
    const float* x = (const float*)d_in[0];
    const float* c = (const float*)d_in[1];

    __half* u0 = (__half*)d_ws;          // NPIX halfs = 12.6 MB
    __half* u1 = u0 + NPIX;              // 12.6 MB
    __half2* xl = (ws_size >= NPIX * 8)
        ? (__half2*)((char*)d_ws + NPIX * 4)
        : (__half2*)d_out;               // safe: per-pixel read-before-write

    dim3 grid(HW / TC, HW / TR, NIMG);   // 4 x 32 x 24 = 3072 blocks
    dim3 block(256);
    sig_step<0><<<grid, block, 0, stream>>>(x, c, nullptr, xl, u0);
    sig_step<1><<<grid, block, 0, stream>>>(x, c, u0, xl, u1);
    sig_step<1><<<grid, block, 0, stream>>>(x, c, u1, xl, u0);
    sig_step<1><<<grid, block, 0, stream>>>(x, c, u0, xl, u1);
    sig_step<1><<<grid, block, 0, stream>>>(x, c, u1, xl, u0);
    sig_step<2><<<grid, block, 0, stream>>>(x, c, u0, xl, d_out);
}

// Round 17
// 105.311 us; speedup vs baseline: 1.0512x; 1.0512x over previous
//
#include <hip/hip_runtime.h>
#include <hip/hip_fp16.h>
#include <math.h>

// sigAct: u0 = sigmoid(-(lam_b*conv(1-2x))/eps); 5 damped updates.
// conv = separable 17-tap Gaussian (sigma=2); folding: conv(1-2u) = 1-2*blur(u)
// with 0.5-padding (== SAME zero-pad of 1-2u).
// Round-17: DUAL GEOMETRY. INIT uses TR=32,TC=64 (r14: tall tile, 1.69x halo
// over-read of f32 x; r16 measured INIT=39.7us at TR=16 from 2.25x f32 fetch).
// MID/FINAL use TR=16,TC=128 (r16: full-wave 256 h-blur units, measured
// 14.2us/step vs r14's 16.7). dot2 both passes, row-paired sP.
// Lessons: VALU-inst-count + phase utilization are the levers (r12/r14/r16);
// occupancy (r11), latency pkgs (r15), fusion (r10), coop (r6) all dead;
// geometry trade is input-width dependent (r16 INIT regression).

#define RAD  8
#define HW   512
#define NIMG 24
#define NPIX ((size_t)HW * HW * NIMG)

typedef _Float16 h2 __attribute__((ext_vector_type(2)));
typedef unsigned int uint;

// 1D normalized Gaussian, sigma=2, 17 taps: exp(-(k-8)^2/8) / 5.0131684
#define G0  6.6916e-05f
#define G1  4.3635e-04f
#define G2  2.2159612e-03f
#define G3  8.7643070e-03f
#define G4  2.6995958e-02f
#define G5  6.4759932e-02f
#define G6  1.2098751e-01f
#define G7  1.7603572e-01f
#define G8  1.9947466e-01f

// sigmoid(-z) = 1/(1+exp(z)); inf->0, -inf->1.
__device__ __forceinline__ float inv1pexp(float z) {
    return __builtin_amdgcn_rcpf(1.0f + __expf(z));
}

__device__ __forceinline__ float fdot2f(uint a, h2 b, float c) {
#if __has_builtin(__builtin_amdgcn_fdot2)
    return __builtin_amdgcn_fdot2(__builtin_bit_cast(h2, a), b, c, false);
#else
    h2 av = __builtin_bit_cast(h2, a);
    return (float)av.x * (float)b.x + (float)av.y * (float)b.y + c;
#endif
}
__device__ __forceinline__ float lo16f(uint v) {
    return __half2float(__ushort_as_half((unsigned short)(v & 0xffffu)));
}
__device__ __forceinline__ float hi16f(uint v) {
    return __half2float(__ushort_as_half((unsigned short)(v >> 16)));
}
__device__ __forceinline__ h2 gpair(int i) {
    // (G[2i], G[2i+1]) fp16, compile-time folded (i = 0..7, taps 0..15)
    const float G[16] = { G0,G1,G2,G3,G4,G5,G6,G7,G8,G7,G6,G5,G4,G3,G2,G1 };
    h2 r; r.x = (_Float16)G[2*i]; r.y = (_Float16)G[2*i+1]; return r;
}
__device__ __forceinline__ uint packh2(float lo, float hi) {
    return __builtin_bit_cast(uint, __floats2half2_rn(lo, hi));
}

// 17-tap dot over a 24-half window (12 even-pairs wv + 11 odd-pairs wo):
// outputs at window offsets 2jp (even) and 2jp+1 (odd).
__device__ __forceinline__ void dot17(const uint* wv, const uint* wo,
                                      int jp, float& aE, float& aO) {
    float a0 = 0.f, a1 = 0.f;
#pragma unroll
    for (int i = 0; i < 8; ++i) {
        h2 g = gpair(i);
        a0 = fdot2f(wv[jp + i], g, a0);
        a1 = fdot2f(wo[jp + i], g, a1);
    }
    aE = fmaf(G0, lo16f(wv[jp + 8]), a0);
    aO = fmaf(G0, hi16f(wv[jp + 8]), a1);
}

template<int MODE, int TR, int TC> // MODE: 0=INIT 1=MID 2=FINAL
__global__ __launch_bounds__(256, 6) void sig_step(
    const float* __restrict__ xg, const float* __restrict__ cgl,
    const __half* __restrict__ uin, __half2* __restrict__ xl,
    void* __restrict__ uout)
{
    constexpr int HP    = (TR + 16) / 2;   // pair-rows in halo
    constexpr int CG    = TC / 8;          // 8-col groups
    constexpr int UNITS = HP * CG;         // h-blur units (<= 256)
    __shared__ uint sP[HP * TC];           // row-paired h-blur output

    const int t    = threadIdx.x;
    const int img  = blockIdx.z;
    const int row0 = blockIdx.y * TR;
    const int col0 = blockIdx.x * TC;
    const size_t ibase = (size_t)img * HW * HW;

    // ===== h-blur: UNITS units = (pair-row rp, col-group ci) =====
    if (UNITS == 256 || t < UNITS) {
        const int rp  = t / CG;
        const int ci  = t % CG;
        const int gc0 = col0 + ci * 8 - RAD;  // window cols [gc0, gc0+24), mult 8
        float aE[2][4], aO[2][4];
#pragma unroll
        for (int rr = 0; rr < 2; ++rr) {
            const int gr = row0 + 2 * rp + rr - RAD;  // halo row in [0, TR+16)
            uint wv[12];
#pragma unroll
            for (int i = 0; i < 12; ++i) wv[i] = 0x38003800u;  // (0.5,0.5) pad
            if (gr >= 0 && gr < HW) {
                if constexpr (MODE == 0) {
                    const float* xb = xg + ibase + (size_t)gr * HW;
#pragma unroll
                    for (int k = 0; k < 6; ++k) {
                        int s = gc0 + 4 * k;
                        if (s >= 0 && s < HW) {
                            float4 v = *reinterpret_cast<const float4*>(&xb[s]);
                            wv[2*k]   = packh2(v.x, v.y);
                            wv[2*k+1] = packh2(v.z, v.w);
                        }
                    }
                } else {
                    const __half* ub = uin + ibase + (size_t)gr * HW;
#pragma unroll
                    for (int k = 0; k < 3; ++k) {
                        int s = gc0 + 8 * k;
                        if (s >= 0 && s < HW) {
                            uint4 v = *reinterpret_cast<const uint4*>(&ub[s]);
                            wv[4*k+0] = v.x; wv[4*k+1] = v.y;
                            wv[4*k+2] = v.z; wv[4*k+3] = v.w;
                        }
                    }
                }
            }
            uint wo[11];
#pragma unroll
            for (int i = 0; i < 11; ++i)
                wo[i] = __builtin_amdgcn_alignbit(wv[i + 1], wv[i], 16);
#pragma unroll
            for (int jp = 0; jp < 4; ++jp)
                dot17(wv, wo, jp, aE[rr][jp], aO[rr][jp]);
        }
        // pack row-pairs: sP[rp][8ci+j] = (row 2rp, row 2rp+1)
        uint4* orow = reinterpret_cast<uint4*>(&sP[rp * TC + ci * 8]);
        orow[0] = make_uint4(packh2(aE[0][0], aE[1][0]), packh2(aO[0][0], aO[1][0]),
                             packh2(aE[0][1], aE[1][1]), packh2(aO[0][1], aO[1][1]));
        orow[1] = make_uint4(packh2(aE[0][2], aE[1][2]), packh2(aO[0][2], aO[1][2]),
                             packh2(aE[0][3], aE[1][3]), packh2(aO[0][3], aO[1][3]));
    }
    __syncthreads();

    // ===== v-blur via dot2 (1 col x 8 rows/thread) + pointwise epilogue =====
    const int cc = t % TC;
    const int rg = t / TC;                 // TR/8 row groups x 8 rows
    const size_t pbase = ibase + (size_t)(row0 + rg * 8) * HW + (col0 + cc);

    uint p[12];                            // pairs rg*4 .. rg*4+11, column cc
#pragma unroll
    for (int j = 0; j < 12; ++j)
        p[j] = sP[(rg * 4 + j) * TC + cc];
    uint po[11];
#pragma unroll
    for (int j = 0; j < 11; ++j)
        po[j] = __builtin_amdgcn_alignbit(p[j + 1], p[j], 16);

#pragma unroll
    for (int jp = 0; jp < 4; ++jp) {
        float vE, vO;
        dot17(p, po, jp, vE, vO);
#pragma unroll
        for (int h = 0; h < 2; ++h) {
            int m = 2 * jp + h;
            float v = h ? vO : vE;
            float f = 1.f - 2.f * v;       // == conv(1-2u), SAME zero-pad

            size_t gidx = pbase + (size_t)m * HW;
            if constexpr (MODE == 0) {
                float xv  = xg[gidx];
                float lam = 100.f * inv1pexp(-10.f * cgl[gidx]); // 100*sig(10c)
                xl[gidx] = __floats2half2_rn(xv, lam);
                ((__half*)uout)[gidx] = __float2half(inv1pexp(lam * f * 0.1f));
            } else {
                float2 pr = __half22float2(xl[gidx]);            // (x, lam)
                float uprev = __half2float(uin[gidx]);           // L1/L2-hot
                float tt = (uprev - pr.x) * 10.f + pr.y * f;     // (u-x)/tau+lam*v
                float uu = inv1pexp(tt * 0.1f);                  // sigmoid(-tt/eps)
                float res = 0.5f * (uprev + uu);                 // alpha = 0.5
                if constexpr (MODE == 2) ((float*)uout)[gidx] = res;
                else                     ((__half*)uout)[gidx] = __float2half(res);
            }
        }
    }
}

extern "C" void kernel_launch(void* const* d_in, const int* in_sizes, int n_in,
                              void* d_out, int out_size, void* d_ws, size_t ws_size,
                              hipStream_t stream) {
    const float* x = (const float*)d_in[0];
    const float* c = (const float*)d_in[1];

    __half* u0 = (__half*)d_ws;          // NPIX halfs = 12.6 MB
    __half* u1 = u0 + NPIX;              // 12.6 MB
    __half2* xl = (ws_size >= NPIX * 8)
        ? (__half2*)((char*)d_ws + NPIX * 4)
        : (__half2*)d_out;               // safe: per-pixel read-before-write

    dim3 block(256);
    dim3 gridI(HW / 64, HW / 32, NIMG);   // INIT: TR=32, TC=64  (8 x 16 x 24)
    dim3 gridM(HW / 128, HW / 16, NIMG);  // MID/FINAL: TR=16, TC=128 (4 x 32 x 24)

    sig_step<0, 32,  64><<<gridI, block, 0, stream>>>(x, c, nullptr, xl, u0);
    sig_step<1, 16, 128><<<gridM, block, 0, stream>>>(x, c, u0, xl, u1);
    sig_step<1, 16, 128><<<gridM, block, 0, stream>>>(x, c, u1, xl, u0);
    sig_step<1, 16, 128><<<gridM, block, 0, stream>>>(x, c, u0, xl, u1);
    sig_step<1, 16, 128><<<gridM, block, 0, stream>>>(x, c, u1, xl, u0);
    sig_step<2, 16, 128><<<gridM, block, 0, stream>>>(x, c, u0, xl, d_out);
}

// Round 18
// 99.317 us; speedup vs baseline: 1.1146x; 1.0603x over previous
//
#include <hip/hip_runtime.h>
#include <hip/hip_fp16.h>
#include <math.h>

// sigAct: u0 = sigmoid(-(lam_b*conv(1-2x))/eps); 5 damped updates.
// conv = separable 17-tap Gaussian (sigma=2); folding: conv(1-2u) = 1-2*blur(u)
// with 0.5-padding (== SAME zero-pad of 1-2u).
// Round-18 = round-14 verbatim (best measured: 99.98us, absmax 0.0156).
// dot2 BOTH passes: h-blur units = 2 rows x 8 cols, output ROW-PAIRED
// sP[24][64] uint = half2(row 2p, row 2p+1); v-blur = 12 ds_read_b32 +
// alignbit + 4x(dot17 pair), f32 accumulation everywhere. Uniform geometry
// across all 6 dispatches (cross-dispatch L2 affinity, r17 lesson: mixing
// geometries costs ~4us). Cost model: INIT ~30us (streaming-floor-bound),
// MID ~14.2us each (geometry-insensitive). Neutral/negative attacks:
// occupancy (r11), latency pkgs (r15), full-wave TR16 (r16 INIT +10us),
// dual geometry (r17 +5us), pair fusion (r10), coop grid.sync (r6).

#define TR   32
#define TC   64
#define RAD  8
#define HW   512
#define NIMG 24
#define NPIX ((size_t)HW * HW * NIMG)

typedef _Float16 h2 __attribute__((ext_vector_type(2)));
typedef unsigned int uint;

// 1D normalized Gaussian, sigma=2, 17 taps: exp(-(k-8)^2/8) / 5.0131684
#define G0  6.6916e-05f
#define G1  4.3635e-04f
#define G2  2.2159612e-03f
#define G3  8.7643070e-03f
#define G4  2.6995958e-02f
#define G5  6.4759932e-02f
#define G6  1.2098751e-01f
#define G7  1.7603572e-01f
#define G8  1.9947466e-01f

// sigmoid(-z) = 1/(1+exp(z)); inf->0, -inf->1.
__device__ __forceinline__ float inv1pexp(float z) {
    return __builtin_amdgcn_rcpf(1.0f + __expf(z));
}

__device__ __forceinline__ float fdot2f(uint a, h2 b, float c) {
#if __has_builtin(__builtin_amdgcn_fdot2)
    return __builtin_amdgcn_fdot2(__builtin_bit_cast(h2, a), b, c, false);
#else
    h2 av = __builtin_bit_cast(h2, a);
    return (float)av.x * (float)b.x + (float)av.y * (float)b.y + c;
#endif
}
__device__ __forceinline__ float lo16f(uint v) {
    return __half2float(__ushort_as_half((unsigned short)(v & 0xffffu)));
}
__device__ __forceinline__ float hi16f(uint v) {
    return __half2float(__ushort_as_half((unsigned short)(v >> 16)));
}
__device__ __forceinline__ h2 gpair(int i) {
    // (G[2i], G[2i+1]) fp16, compile-time folded (i = 0..7, taps 0..15)
    const float G[16] = { G0,G1,G2,G3,G4,G5,G6,G7,G8,G7,G6,G5,G4,G3,G2,G1 };
    h2 r; r.x = (_Float16)G[2*i]; r.y = (_Float16)G[2*i+1]; return r;
}
__device__ __forceinline__ uint packh2(float lo, float hi) {
    return __builtin_bit_cast(uint, __floats2half2_rn(lo, hi));
}

// 17-tap dot over a 24-half window (12 even-pairs wv + 11 odd-pairs wo):
// outputs at window offsets 2jp (even) and 2jp+1 (odd).
__device__ __forceinline__ void dot17(const uint* wv, const uint* wo,
                                      int jp, float& aE, float& aO) {
    float a0 = 0.f, a1 = 0.f;
#pragma unroll
    for (int i = 0; i < 8; ++i) {
        h2 g = gpair(i);
        a0 = fdot2f(wv[jp + i], g, a0);
        a1 = fdot2f(wo[jp + i], g, a1);
    }
    aE = fmaf(G0, lo16f(wv[jp + 8]), a0);
    aO = fmaf(G0, hi16f(wv[jp + 8]), a1);
}

template<int MODE> // 0=INIT 1=MID 2=FINAL
__global__ __launch_bounds__(256, 6) void sig_step(
    const float* __restrict__ xg, const float* __restrict__ cgl,
    const __half* __restrict__ uin, __half2* __restrict__ xl,
    void* __restrict__ uout)
{
    __shared__ uint sP[24 * 64];   // row-paired h-blur output, 6 KB

    const int t    = threadIdx.x;
    const int img  = blockIdx.z;
    const int row0 = blockIdx.y * TR;
    const int col0 = blockIdx.x * TC;
    const size_t ibase = (size_t)img * HW * HW;

    // ===== h-blur: 192 units = (pair-row rp in [0,24), 8-col group ci) =====
    if (t < 192) {
        const int rp  = t >> 3;               // 0..23
        const int ci  = t & 7;                // 0..7
        const int gc0 = col0 + ci * 8 - RAD;  // window cols [gc0, gc0+24), mult 8
        float aE[2][4], aO[2][4];
#pragma unroll
        for (int rr = 0; rr < 2; ++rr) {
            const int gr = row0 + 2 * rp + rr - RAD;  // halo row 2rp+rr in [0,48)
            uint wv[12];
#pragma unroll
            for (int i = 0; i < 12; ++i) wv[i] = 0x38003800u;  // (0.5,0.5) pad
            if (gr >= 0 && gr < HW) {
                if constexpr (MODE == 0) {
                    const float* xb = xg + ibase + (size_t)gr * HW;
#pragma unroll
                    for (int k = 0; k < 6; ++k) {
                        int s = gc0 + 4 * k;
                        if (s >= 0 && s < HW) {
                            float4 v = *reinterpret_cast<const float4*>(&xb[s]);
                            wv[2*k]   = packh2(v.x, v.y);
                            wv[2*k+1] = packh2(v.z, v.w);
                        }
                    }
                } else {
                    const __half* ub = uin + ibase + (size_t)gr * HW;
#pragma unroll
                    for (int k = 0; k < 3; ++k) {
                        int s = gc0 + 8 * k;
                        if (s >= 0 && s < HW) {
                            uint4 v = *reinterpret_cast<const uint4*>(&ub[s]);
                            wv[4*k+0] = v.x; wv[4*k+1] = v.y;
                            wv[4*k+2] = v.z; wv[4*k+3] = v.w;
                        }
                    }
                }
            }
            uint wo[11];
#pragma unroll
            for (int i = 0; i < 11; ++i)
                wo[i] = __builtin_amdgcn_alignbit(wv[i + 1], wv[i], 16);
#pragma unroll
            for (int jp = 0; jp < 4; ++jp)
                dot17(wv, wo, jp, aE[rr][jp], aO[rr][jp]);
        }
        // pack row-pairs: sP[rp][8ci+j] = (row 2rp, row 2rp+1)
        uint4* orow = reinterpret_cast<uint4*>(&sP[rp * 64 + ci * 8]);
        orow[0] = make_uint4(packh2(aE[0][0], aE[1][0]), packh2(aO[0][0], aO[1][0]),
                             packh2(aE[0][1], aE[1][1]), packh2(aO[0][1], aO[1][1]));
        orow[1] = make_uint4(packh2(aE[0][2], aE[1][2]), packh2(aO[0][2], aO[1][2]),
                             packh2(aE[0][3], aE[1][3]), packh2(aO[0][3], aO[1][3]));
    }
    __syncthreads();

    // ===== v-blur via dot2 (1 col x 8 rows/thread) + pointwise epilogue =====
    const int cc = t & 63;
    const int rg = t >> 6;                 // 4 row groups x 8 rows
    const size_t pbase = ibase + (size_t)(row0 + rg * 8) * HW + (col0 + cc);

    uint p[12];                            // pairs rg*4 .. rg*4+11, column cc
#pragma unroll
    for (int j = 0; j < 12; ++j)
        p[j] = sP[(rg * 4 + j) * 64 + cc];
    uint po[11];
#pragma unroll
    for (int j = 0; j < 11; ++j)
        po[j] = __builtin_amdgcn_alignbit(p[j + 1], p[j], 16);

#pragma unroll
    for (int jp = 0; jp < 4; ++jp) {
        float vE, vO;
        dot17(p, po, jp, vE, vO);
#pragma unroll
        for (int h = 0; h < 2; ++h) {
            int m = 2 * jp + h;
            float v = h ? vO : vE;
            float f = 1.f - 2.f * v;       // == conv(1-2u), SAME zero-pad

            size_t gidx = pbase + (size_t)m * HW;
            if constexpr (MODE == 0) {
                float xv  = xg[gidx];
                float lam = 100.f * inv1pexp(-10.f * cgl[gidx]); // 100*sig(10c)
                xl[gidx] = __floats2half2_rn(xv, lam);
                ((__half*)uout)[gidx] = __float2half(inv1pexp(lam * f * 0.1f));
            } else {
                float2 pr = __half22float2(xl[gidx]);            // (x, lam)
                float uprev = __half2float(uin[gidx]);           // L1/L2-hot
                float tt = (uprev - pr.x) * 10.f + pr.y * f;     // (u-x)/tau+lam*v
                float uu = inv1pexp(tt * 0.1f);                  // sigmoid(-tt/eps)
                float res = 0.5f * (uprev + uu);                 // alpha = 0.5
                if constexpr (MODE == 2) ((float*)uout)[gidx] = res;
                else                     ((__half*)uout)[gidx] = __float2half(res);
            }
        }
    }
}

extern "C" void kernel_launch(void* const* d_in, const int* in_sizes, int n_in,
                              void* d_out, int out_size, void* d_ws, size_t ws_size,
                              hipStream_t stream) {
    const float* x = (const float*)d_in[0];
    const float* c = (const float*)d_in[1];

    __half* u0 = (__half*)d_ws;          // NPIX halfs = 12.6 MB
    __half* u1 = u0 + NPIX;              // 12.6 MB
    __half2* xl = (ws_size >= NPIX * 8)
        ? (__half2*)((char*)d_ws + NPIX * 4)
        : (__half2*)d_out;               // safe: per-pixel read-before-write

    dim3 grid(HW / TC, HW / TR, NIMG);   // 8 x 16 x 24 = 3072 blocks
    dim3 block(256);
    sig_step<0><<<grid, block, 0, stream>>>(x, c, nullptr, xl, u0);
    sig_step<1><<<grid, block, 0, stream>>>(x, c, u0, xl, u1);
    sig_step<1><<<grid, block, 0, stream>>>(x, c, u1, xl, u0);
    sig_step<1><<<grid, block, 0, stream>>>(x, c, u0, xl, u1);
    sig_step<1><<<grid, block, 0, stream>>>(x, c, u1, xl, u0);
    sig_step<2><<<grid, block, 0, stream>>>(x, c, u0, xl, d_out);
}